// Round 5
// baseline (463.282 us; speedup 1.0000x reference)
//
#include <hip/hip_runtime.h>
#include <math.h>

#define B_ 8
#define K_ 100000
#define NANN 32
#define C_ 80
#define BLOCK 256
#define LN2 0.69314718056f

// ws layout (floats): [0..24) per-batch {cls, reg, npos}
__global__ void zero_ws_kernel(float* ws) {
    int i = threadIdx.x;
    if (i < 3 * B_) ws[i] = 0.0f;
}

__device__ __forceinline__ float fast_log2(float x) {
#if __has_builtin(__builtin_amdgcn_logf)
    return __builtin_amdgcn_logf(x);      // raw v_log_f32 (log2)
#else
    return __log2f(x);
#endif
}
__device__ __forceinline__ float fast_sqrt(float x) {
#if __has_builtin(__builtin_amdgcn_sqrtf)
    return __builtin_amdgcn_sqrtf(x);     // raw v_sqrt_f32
#else
    return sqrtf(x);
#endif
}

// -------- Phase A: unconditional streaming reduce over ALL of cls ----------
// Computes (-0.75*ln2) * sum sqrt(p)*log2(1-p) per batch. No mask, no LDS
// dependency, no divide: pure BW-bound reduce with 8 loads in flight/thread.
#define SLAB 2000                          // float4 per block (32 KB)
#define SW_GX 1000                         // SLAB * SW_GX = 2,000,000 = K_*C_/4

__launch_bounds__(BLOCK, 4)
__global__ void focal_sweep(const float* __restrict__ cls,
                            float* __restrict__ ws) {
    const int b   = blockIdx.y;
    const int tid = threadIdx.x;
    const float4* __restrict__ cp =
        (const float4*)(cls + (size_t)b * (K_ * C_)) + (size_t)blockIdx.x * SLAB;

    float4 x[8];
#pragma unroll
    for (int j = 0; j < 8; ++j) {
        x[j] = make_float4(0.0f, 0.0f, 0.0f, 0.0f);   // p=0 contributes exactly 0
        int idx = j * BLOCK + tid;
        if (idx < SLAB) x[j] = cp[idx];
    }

    float a0 = 0.0f, a1 = 0.0f, a2 = 0.0f, a3 = 0.0f;
#pragma unroll
    for (int j = 0; j < 8; ++j) {
        a0 += fast_sqrt(x[j].x) * fast_log2(1.0f - x[j].x);
        a1 += fast_sqrt(x[j].y) * fast_log2(1.0f - x[j].y);
        a2 += fast_sqrt(x[j].z) * fast_log2(1.0f - x[j].z);
        a3 += fast_sqrt(x[j].w) * fast_log2(1.0f - x[j].w);
    }
    float v = ((a0 + a1) + (a2 + a3)) * (-0.75f * LN2);

    __shared__ float s_red[BLOCK / 64];
    for (int off = 32; off > 0; off >>= 1)
        v += __shfl_down(v, off, 64);
    int wave = tid >> 6, lane = tid & 63;
    if (lane == 0) s_red[wave] = v;
    __syncthreads();
    if (tid == 0) {
        float c = 0.0f;
        for (int w = 0; w < BLOCK / 64; ++w) c += s_red[w];
        atomicAdd(&ws[b * 3 + 0], c);
    }
}

// -------- Phase B: per-anchor assignment + sparse corrections --------------
__launch_bounds__(BLOCK)
__global__ void focal_assign(const float* __restrict__ cls,
                             const float* __restrict__ reg,
                             const float* __restrict__ anc,
                             const float* __restrict__ ann,
                             float* __restrict__ ws) {
    const int b   = blockIdx.y;
    const int tid = threadIdx.x;
    const int k   = blockIdx.x * BLOCK + tid;

    __shared__ float s_ann[NANN * 5];
    __shared__ float s_red[(BLOCK / 64) * 3];

    if (tid < NANN * 5) s_ann[tid] = ann[b * NANN * 5 + tid];
    __syncthreads();

    float reg_acc  = 0.0f;
    float np_acc   = 0.0f;
    float cls_corr = 0.0f;

    if (k < K_) {
        float4 a = *(const float4*)(anc + (size_t)k * 4);
        float aw = a.z - a.x, ah = a.w - a.y;
        float area_a = aw * ah;

        float best = -2.0f;
        int bestj = 0;
        for (int j = 0; j < NANN; ++j) {
            float bx1 = s_ann[j * 5 + 0], by1 = s_ann[j * 5 + 1];
            float bx2 = s_ann[j * 5 + 2], by2 = s_ann[j * 5 + 3];
            float lbl = s_ann[j * 5 + 4];
            float area_b = (bx2 - bx1) * (by2 - by1);
            float iw = fmaxf(fminf(a.z, bx2) - fmaxf(a.x, bx1), 0.0f);
            float ih = fmaxf(fminf(a.w, by2) - fmaxf(a.y, by1), 0.0f);
            float inter = iw * ih;
            float uni = fmaxf(area_a + area_b - inter, 1e-8f);
            float iou = inter / uni;
            if (lbl < 0.0f) iou = -1.0f;            // invalid annotation mask
            if (iou > best) { best = iou; bestj = j; }  // first-max = jnp.argmax
        }

        if (best >= 0.5f) {                         // positive anchor
            np_acc = 1.0f;
            int c = (int)s_ann[bestj * 5 + 4];
            // sweep applied the NEG formula at class c; swap for POS formula.
            float p  = cls[((size_t)b * K_ + k) * C_ + c];
            float pm = 1.0f - p;
            float pos_term = -0.25f * fast_sqrt(pm) * (fast_log2(p)  * LN2);
            float neg_term = -0.75f * fast_sqrt(p)  * (fast_log2(pm) * LN2);
            cls_corr = pos_term - neg_term;

            // regression smooth-L1
            float gx1 = s_ann[bestj * 5 + 0], gy1 = s_ann[bestj * 5 + 1];
            float gx2 = s_ann[bestj * 5 + 2], gy2 = s_ann[bestj * 5 + 3];
            float gw = fmaxf(gx2 - gx1, 1.0f);
            float gh = fmaxf(gy2 - gy1, 1.0f);
            float gcx = gx1 + 0.5f * gw, gcy = gy1 + 0.5f * gh;
            float acx = a.x + 0.5f * aw, acy = a.y + 0.5f * ah;
            float4 r = *(const float4*)(reg + ((size_t)b * K_ + k) * 4);
            float t0 = ((gcx - acx) / aw) * 10.0f;
            float t1 = ((gcy - acy) / ah) * 10.0f;
            float t2 = (fast_log2(gw / aw) * LN2) * 5.0f;
            float t3 = (fast_log2(gh / ah) * LN2) * 5.0f;
            float d, s;
            d = fabsf(t0 - r.x); s = (d <= 1.0f/9.0f) ? 4.5f*d*d : d - 0.5f/9.0f; reg_acc += s;
            d = fabsf(t1 - r.y); s = (d <= 1.0f/9.0f) ? 4.5f*d*d : d - 0.5f/9.0f; reg_acc += s;
            d = fabsf(t2 - r.z); s = (d <= 1.0f/9.0f) ? 4.5f*d*d : d - 0.5f/9.0f; reg_acc += s;
            d = fabsf(t3 - r.w); s = (d <= 1.0f/9.0f) ? 4.5f*d*d : d - 0.5f/9.0f; reg_acc += s;
        } else if (best >= 0.4f) {                  // IGNORED anchor: remove its row
            const float4* __restrict__ rp =
                (const float4*)(cls + ((size_t)b * K_ + k) * C_);
            float r0 = 0.0f, r1 = 0.0f, r2 = 0.0f, r3 = 0.0f;
#pragma unroll
            for (int j = 0; j < C_ / 4; ++j) {
                float4 x = rp[j];
                r0 += fast_sqrt(x.x) * fast_log2(1.0f - x.x);
                r1 += fast_sqrt(x.y) * fast_log2(1.0f - x.y);
                r2 += fast_sqrt(x.z) * fast_log2(1.0f - x.z);
                r3 += fast_sqrt(x.w) * fast_log2(1.0f - x.w);
            }
            // cancel (-0.75*ln2)*rowsum added by the sweep
            cls_corr = (0.75f * LN2) * ((r0 + r1) + (r2 + r3));
        } // negative anchor: sweep's contribution is already correct
    }

    // block reduction of (cls_corr, reg_acc, np_acc)
    float v0 = cls_corr, v1 = reg_acc, v2 = np_acc;
    for (int off = 32; off > 0; off >>= 1) {
        v0 += __shfl_down(v0, off, 64);
        v1 += __shfl_down(v1, off, 64);
        v2 += __shfl_down(v2, off, 64);
    }
    int wave = tid >> 6, lane = tid & 63;
    if (lane == 0) {
        s_red[wave * 3 + 0] = v0;
        s_red[wave * 3 + 1] = v1;
        s_red[wave * 3 + 2] = v2;
    }
    __syncthreads();
    if (tid == 0) {
        float c = 0.0f, rg = 0.0f, np = 0.0f;
        for (int w = 0; w < BLOCK / 64; ++w) {
            c  += s_red[w * 3 + 0];
            rg += s_red[w * 3 + 1];
            np += s_red[w * 3 + 2];
        }
        atomicAdd(&ws[b * 3 + 0], c);
        atomicAdd(&ws[b * 3 + 1], rg);
        atomicAdd(&ws[b * 3 + 2], np);
    }
}

__global__ void finalize_kernel(const float* __restrict__ ws, float* __restrict__ out) {
    if (threadIdx.x == 0) {
        float cs = 0.0f, rs = 0.0f;
        for (int b = 0; b < B_; ++b) {
            float c  = ws[b * 3 + 0];
            float r  = ws[b * 3 + 1];
            float np = ws[b * 3 + 2];
            cs += c / fmaxf(np, 1.0f);
            rs += (np > 0.0f) ? r / fmaxf(np * 4.0f, 1.0f) : 0.0f;
        }
        out[0] = cs / (float)B_;
        out[1] = rs / (float)B_;
    }
}

extern "C" void kernel_launch(void* const* d_in, const int* in_sizes, int n_in,
                              void* d_out, int out_size, void* d_ws, size_t ws_size,
                              hipStream_t stream) {
    const float* cls = (const float*)d_in[0];   // [B,K,C]
    const float* reg = (const float*)d_in[1];   // [B,K,4]
    const float* anc = (const float*)d_in[2];   // [1,K,4]
    const float* ann = (const float*)d_in[3];   // [B,NANN,5]
    float* out = (float*)d_out;                  // [2]
    float* ws  = (float*)d_ws;                   // 24 floats

    zero_ws_kernel<<<1, 64, 0, stream>>>(ws);

    dim3 g2(SW_GX, B_);
    focal_sweep<<<g2, BLOCK, 0, stream>>>(cls, ws);

    dim3 g1((K_ + BLOCK - 1) / BLOCK, B_);
    focal_assign<<<g1, BLOCK, 0, stream>>>(cls, reg, anc, ann, ws);

    finalize_kernel<<<1, 64, 0, stream>>>(ws, out);
}

// Round 6
// 378.598 us; speedup vs baseline: 1.2237x; 1.2237x over previous
//
#include <hip/hip_runtime.h>
#include <math.h>

#define B_ 8
#define K_ 100000
#define NANN 32
#define C_ 80
#define BLOCK 256
#define CHUNK 256           // anchors per block (== BLOCK)
#define NIT 20              // float4 per thread in sweep (CHUNK*C_/4/BLOCK)
#define LN2 0.69314718056f

__global__ void zero_ws_kernel(float* ws) {
    int i = threadIdx.x;
    if (i < 3 * B_) ws[i] = 0.0f;
}

__device__ __forceinline__ float fast_log2(float x) {
#if __has_builtin(__builtin_amdgcn_logf)
    return __builtin_amdgcn_logf(x);      // raw v_log_f32 (log2)
#else
    return __log2f(x);
#endif
}
__device__ __forceinline__ float fast_sqrt(float x) {
#if __has_builtin(__builtin_amdgcn_sqrtf)
    return __builtin_amdgcn_sqrtf(x);     // raw v_sqrt_f32
#else
    return sqrtf(x);
#endif
}

__launch_bounds__(BLOCK)
__global__ void focal_main(const float* __restrict__ cls,
                           const float* __restrict__ reg,
                           const float* __restrict__ anc,
                           const float* __restrict__ ann,
                           float* __restrict__ ws) {
    const int b     = blockIdx.y;
    const int chunk = blockIdx.x;
    const int tid   = threadIdx.x;

    __shared__ float s_ann[NANN * 5];
    __shared__ float s_m[CHUNK];               // 0 = ignore, 1 = count
    __shared__ float s_red[(BLOCK / 64) * 3];

    if (tid < NANN * 5) s_ann[tid] = ann[b * NANN * 5 + tid];
    __syncthreads();

    const int k0 = chunk * CHUNK;
    const int k  = k0 + tid;

    float reg_acc  = 0.0f;
    float np_acc   = 0.0f;
    float cls_corr = 0.0f;
    float m        = 0.0f;

    if (k < K_) {
        float4 a = *(const float4*)(anc + (size_t)k * 4);
        float aw = a.z - a.x, ah = a.w - a.y;
        float area_a = aw * ah;

        // division-free first-argmax over IoU: track (bi,bu) ~ best inter/union
        float bi = -2.0f, bu = 1.0f;
        int bestj = 0;
        for (int j = 0; j < NANN; ++j) {
            float bx1 = s_ann[j * 5 + 0], by1 = s_ann[j * 5 + 1];
            float bx2 = s_ann[j * 5 + 2], by2 = s_ann[j * 5 + 3];
            float lbl = s_ann[j * 5 + 4];
            float area_b = (bx2 - bx1) * (by2 - by1);
            float iw = fmaxf(fminf(a.z, bx2) - fmaxf(a.x, bx1), 0.0f);
            float ih = fmaxf(fminf(a.w, by2) - fmaxf(a.y, by1), 0.0f);
            float inter = iw * ih;
            float uni = fmaxf(area_a + area_b - inter, 1e-8f);
            if (lbl < 0.0f) { inter = -1.0f; uni = 1.0f; }   // invalid ann
            if (inter * bu > bi * uni) { bi = inter; bu = uni; bestj = j; }
        }

        bool positive = (bi >= 0.5f * bu);     // iou_max >= 0.5
        bool negative = (bi < 0.4f * bu);      // iou_max < 0.4 (incl. all-masked)

        if (positive) {
            m = 1.0f;
            np_acc = 1.0f;
            int c = (int)s_ann[bestj * 5 + 4];
            // sweep applies NEG formula at class c; swap for POS formula here.
            float p  = cls[((size_t)b * K_ + k) * C_ + c];
            float pm = 1.0f - p;
            float pos_term = -0.25f * fast_sqrt(pm) * (fast_log2(p)  * LN2);
            float neg_term = -0.75f * fast_sqrt(p)  * (fast_log2(pm) * LN2);
            cls_corr = pos_term - neg_term;

            // regression smooth-L1
            float gx1 = s_ann[bestj * 5 + 0], gy1 = s_ann[bestj * 5 + 1];
            float gx2 = s_ann[bestj * 5 + 2], gy2 = s_ann[bestj * 5 + 3];
            float gw = fmaxf(gx2 - gx1, 1.0f);
            float gh = fmaxf(gy2 - gy1, 1.0f);
            float gcx = gx1 + 0.5f * gw, gcy = gy1 + 0.5f * gh;
            float acx = a.x + 0.5f * aw, acy = a.y + 0.5f * ah;
            float4 r = *(const float4*)(reg + ((size_t)b * K_ + k) * 4);
            float t0 = ((gcx - acx) / aw) * 10.0f;
            float t1 = ((gcy - acy) / ah) * 10.0f;
            float t2 = (fast_log2(gw / aw) * LN2) * 5.0f;
            float t3 = (fast_log2(gh / ah) * LN2) * 5.0f;
            float d, s;
            d = fabsf(t0 - r.x); s = (d <= 1.0f/9.0f) ? 4.5f*d*d : d - 0.5f/9.0f; reg_acc += s;
            d = fabsf(t1 - r.y); s = (d <= 1.0f/9.0f) ? 4.5f*d*d : d - 0.5f/9.0f; reg_acc += s;
            d = fabsf(t2 - r.z); s = (d <= 1.0f/9.0f) ? 4.5f*d*d : d - 0.5f/9.0f; reg_acc += s;
            d = fabsf(t3 - r.w); s = (d <= 1.0f/9.0f) ? 4.5f*d*d : d - 0.5f/9.0f; reg_acc += s;
        } else if (negative) {
            m = 1.0f;
        } // else ignore: m = 0
    }
    s_m[tid] = m;
    __syncthreads();

    // ---- classification sweep: acc = sum m * sqrt(p) * log2(1-p) ----
    const int na  = min(CHUNK, K_ - k0);
    const int nf4 = na * (C_ / 4);
    const float4* __restrict__ cp =
        (const float4*)(cls + ((size_t)b * K_ + (size_t)k0) * C_);

    float a0 = 0.0f, a1 = 0.0f, a2 = 0.0f, a3 = 0.0f;

    if (na == CHUNK) {
        // hoist all 20 mask reads: one batched LDS group, no per-iter latency
        float msk[NIT];
#pragma unroll
        for (int it = 0; it < NIT; ++it) {
            int idx = tid + it * BLOCK;
            msk[it] = s_m[(idx * 3277) >> 16];   // idx/20, exact for idx<5120
        }
#pragma unroll
        for (int g = 0; g < 4; ++g) {
            float4 x[5];
#pragma unroll
            for (int i = 0; i < 5; ++i)
                x[i] = cp[tid + (g * 5 + i) * BLOCK];
#pragma unroll
            for (int i = 0; i < 5; ++i) {
                float mm = msk[g * 5 + i];
                a0 = fmaf(mm, fast_sqrt(x[i].x) * fast_log2(1.0f - x[i].x), a0);
                a1 = fmaf(mm, fast_sqrt(x[i].y) * fast_log2(1.0f - x[i].y), a1);
                a2 = fmaf(mm, fast_sqrt(x[i].z) * fast_log2(1.0f - x[i].z), a2);
                a3 = fmaf(mm, fast_sqrt(x[i].w) * fast_log2(1.0f - x[i].w), a3);
            }
        }
    } else {
        for (int idx = tid; idx < nf4; idx += BLOCK) {
            int a_l = (idx * 3277) >> 16;
            float mm = s_m[a_l];
            float4 x = cp[idx];
            a0 = fmaf(mm, fast_sqrt(x.x) * fast_log2(1.0f - x.x), a0);
            a1 = fmaf(mm, fast_sqrt(x.y) * fast_log2(1.0f - x.y), a1);
            a2 = fmaf(mm, fast_sqrt(x.z) * fast_log2(1.0f - x.z), a2);
            a3 = fmaf(mm, fast_sqrt(x.w) * fast_log2(1.0f - x.w), a3);
        }
    }

    float cls_acc = ((a0 + a1) + (a2 + a3)) * (-0.75f * LN2) + cls_corr;

    // ---- block reduction of (cls_acc, reg_acc, np_acc) ----
    float v0 = cls_acc, v1 = reg_acc, v2 = np_acc;
    for (int off = 32; off > 0; off >>= 1) {
        v0 += __shfl_down(v0, off, 64);
        v1 += __shfl_down(v1, off, 64);
        v2 += __shfl_down(v2, off, 64);
    }
    int wave = tid >> 6, lane = tid & 63;
    if (lane == 0) {
        s_red[wave * 3 + 0] = v0;
        s_red[wave * 3 + 1] = v1;
        s_red[wave * 3 + 2] = v2;
    }
    __syncthreads();
    if (tid == 0) {
        float c = 0.0f, rg = 0.0f, np = 0.0f;
        for (int w = 0; w < BLOCK / 64; ++w) {
            c  += s_red[w * 3 + 0];
            rg += s_red[w * 3 + 1];
            np += s_red[w * 3 + 2];
        }
        atomicAdd(&ws[b * 3 + 0], c);
        atomicAdd(&ws[b * 3 + 1], rg);
        atomicAdd(&ws[b * 3 + 2], np);
    }
}

__global__ void finalize_kernel(const float* __restrict__ ws, float* __restrict__ out) {
    if (threadIdx.x == 0) {
        float cs = 0.0f, rs = 0.0f;
        for (int b = 0; b < B_; ++b) {
            float c  = ws[b * 3 + 0];
            float r  = ws[b * 3 + 1];
            float np = ws[b * 3 + 2];
            cs += c / fmaxf(np, 1.0f);
            rs += (np > 0.0f) ? r / fmaxf(np * 4.0f, 1.0f) : 0.0f;
        }
        out[0] = cs / (float)B_;
        out[1] = rs / (float)B_;
    }
}

extern "C" void kernel_launch(void* const* d_in, const int* in_sizes, int n_in,
                              void* d_out, int out_size, void* d_ws, size_t ws_size,
                              hipStream_t stream) {
    const float* cls = (const float*)d_in[0];   // [B,K,C]
    const float* reg = (const float*)d_in[1];   // [B,K,4]
    const float* anc = (const float*)d_in[2];   // [1,K,4]
    const float* ann = (const float*)d_in[3];   // [B,NANN,5]
    float* out = (float*)d_out;                  // [2]
    float* ws  = (float*)d_ws;                   // 24 floats

    zero_ws_kernel<<<1, 64, 0, stream>>>(ws);

    dim3 grid((K_ + CHUNK - 1) / CHUNK, B_);
    focal_main<<<grid, BLOCK, 0, stream>>>(cls, reg, anc, ann, ws);

    finalize_kernel<<<1, 64, 0, stream>>>(ws, out);
}